// Round 1
// baseline (254.996 us; speedup 1.0000x reference)
//
#include <hip/hip_runtime.h>

#define N_NODES 50000
#define N_EDGES 800000
#define DIM 64
#define N_LAYERS 3
#define N_GRAPHS 256
#define BN_EPS 1e-5f
#define D3 (DIM * N_LAYERS)
#define N_PART 8
#define NBKT 782          // ceil(50000/64) destination buckets
#define NPB 196           // partition blocks (4096 edges each)
#define ECAP 2048         // fixed capacity per bucket (mean 1023, sigma ~32)
#define CVT_BLOCKS 3125   // convert_x blocks (800,000 float4 / 256)
#define PREP_BLOCKS 96    // prep_weights blocks (24,576 / 256)
#define ZF4 13056         // float4s to zero: (3*8*128 + 3*256*64)/4

typedef __attribute__((ext_vector_type(8))) short short8;
typedef __attribute__((ext_vector_type(4))) float floatx4;

// ---------------------------------------------------------- bf16 split utils
__device__ inline unsigned short bf16_rn(float f) {
    unsigned u = __float_as_uint(f);
    u += 0x7FFF + ((u >> 16) & 1);
    return (unsigned short)(u >> 16);
}
__device__ inline float bf16_f(unsigned short b) {
    return __uint_as_float(((unsigned)b) << 16);
}
__device__ inline void split8(float4 a, float4 b, short8* hi, short8* lo) {
    float v[8] = {a.x, a.y, a.z, a.w, b.x, b.y, b.z, b.w};
#pragma unroll
    for (int i = 0; i < 8; i++) {
        unsigned short h = bf16_rn(v[i]);
        (*hi)[i] = (short)h;
        (*lo)[i] = (short)bf16_rn(v[i] - bf16_f(h));
    }
}

// -------- pass 1: per-block LDS hist -> counts[bucket][block]; also zeros
// the sums_part/praw accumulator region (replaces a hipMemsetAsync dispatch)
__global__ __launch_bounds__(256) void pass1_hist(const int* __restrict__ dst,
                                                  int* __restrict__ counts,
                                                  float4* __restrict__ zbuf) {
    int zi = blockIdx.x * 256 + threadIdx.x;
    if (zi < ZF4) zbuf[zi] = (float4){0.f, 0.f, 0.f, 0.f};
    __shared__ int hcnt[NBKT];
    for (int i = threadIdx.x; i < NBKT; i += 256) hcnt[i] = 0;
    __syncthreads();
    int base = blockIdx.x * 4096;
#pragma unroll
    for (int k = 0; k < 16; k++) {
        int e = base + k * 256 + threadIdx.x;
        if (e < N_EDGES) atomicAdd(&hcnt[dst[e] >> 6], 1);   // LDS atomic (native)
    }
    __syncthreads();
    for (int i = threadIdx.x; i < NBKT; i += 256)
        counts[i * NPB + blockIdx.x] = hcnt[i];
}

// -------- per-bucket exclusive scan over the 196 block counts -> offs, totals
__global__ __launch_bounds__(256) void bucket_scan(const int* __restrict__ counts,
                                                   int* __restrict__ offs,
                                                   int* __restrict__ bcnt) {
    __shared__ int s[256];
    int b = blockIdx.x, t = threadIdx.x;
    int v = (t < NPB) ? counts[b * NPB + t] : 0;
    s[t] = v;
    __syncthreads();
    for (int off = 1; off < 256; off <<= 1) {
        int u = (t >= off) ? s[t - off] : 0;
        __syncthreads();
        s[t] += u;
        __syncthreads();
    }
    if (t < NPB) offs[b * NPB + t] = s[t] - v;
    if (t == NPB - 1) bcnt[b] = s[t];
}

// -------- pass 2: deterministic scatter via LDS position counters
__global__ __launch_bounds__(256) void pass2_scatter(const int* __restrict__ src,
                                                     const int* __restrict__ dst,
                                                     const int* __restrict__ offs,
                                                     unsigned* __restrict__ ebuf) {
    __shared__ int loff[NBKT];
    int blk = blockIdx.x;
    for (int i = threadIdx.x; i < NBKT; i += 256)
        loff[i] = offs[i * NPB + blk];
    __syncthreads();
    int base = blk * 4096;
#pragma unroll
    for (int k = 0; k < 16; k++) {
        int e = base + k * 256 + threadIdx.x;
        if (e < N_EDGES) {
            int d = dst[e];
            int b = d >> 6;
            int pos = atomicAdd(&loff[b], 1);     // LDS int atomic (native)
            ebuf[(size_t)b * ECAP + pos] = ((unsigned)src[e] << 6) | (unsigned)(d & 63);
        }
    }
}

// ===== fused: bucket counting-sort (blocks [0,NBKT)) + setup work
__global__ __launch_bounds__(256) void sort_and_setup(
    const unsigned* __restrict__ ebuf, const int* __restrict__ bcnt,
    int* __restrict__ csr, int* __restrict__ rp2,
    const float* __restrict__ x, unsigned short* __restrict__ xb,
    const float* __restrict__ W1, const float* __restrict__ W2,
    unsigned short* __restrict__ wf,
    const int* __restrict__ batch, int* __restrict__ cntg) {
    int blk = blockIdx.x, tid = threadIdx.x;

    if (blk < NBKT) {                     // ---- bucket counting sort
        __shared__ unsigned ent[ECAP];
        __shared__ int cnt[64], basea[64], fill[64];
        int b = blk;
        int start = b * ECAP;
        int T = bcnt[b];
        const unsigned* eb = ebuf + (size_t)b * ECAP;
        if (tid < 64) cnt[tid] = 0;
        for (int i = tid; i < T; i += 256) ent[i] = eb[i];
        __syncthreads();
        for (int i = tid; i < T; i += 256) atomicAdd(&cnt[ent[i] & 63], 1);
        __syncthreads();
        if (tid < 64) {
            int v = cnt[tid], xp = v;
#pragma unroll
            for (int off = 1; off < 64; off <<= 1) {
                int y = __shfl_up(xp, off);
                if (tid >= off) xp += y;
            }
            basea[tid] = xp - v;
            fill[tid] = 0;
            rp2[b * 65 + tid] = start + xp - v;
            if (tid == 63) rp2[b * 65 + 64] = start + xp;
        }
        __syncthreads();
        for (int i = tid; i < T; i += 256) {
            unsigned e = ent[i];
            int c = e & 63;
            int pos = basea[c] + atomicAdd(&fill[c], 1);
            csr[start + pos] = (int)(e >> 6);
        }
        return;
    }
    int sb = blk - NBKT;
    if (sb < CVT_BLOCKS) {                // ---- convert x to bf16
        int i = sb * 256 + tid;
        float4 v = ((const float4*)x)[i];
        ushort4 o;
        o.x = bf16_rn(v.x); o.y = bf16_rn(v.y);
        o.z = bf16_rn(v.z); o.w = bf16_rn(v.w);
        ((ushort4*)xb)[i] = o;
        return;
    }
    sb -= CVT_BLOCKS;
    if (sb < PREP_BLOCKS) {               // ---- pack weight fragments
        int idx = sb * 256 + tid;
        int j    = idx & 7;
        int lane = (idx >> 3) & 63;
        int ks   = (idx >> 9) & 1;
        int nt   = (idx >> 10) & 3;
        int gemm = (idx >> 12) & 1;
        int layer = idx >> 13;
        int n = nt * 16 + (lane & 15);
        int k = ks * 32 + (lane >> 4) * 8 + j;
        const float* W = (gemm ? W2 : W1) + (size_t)layer * DIM * DIM;
        float w = W[k * DIM + n];
        unsigned short hi = bf16_rn(w);
        unsigned short lo = bf16_rn(w - bf16_f(hi));
        size_t base = ((size_t)layer * 2 + gemm) * 8192;
        int f = nt * 2 + ks;
        wf[base + f * 512 + lane * 8 + j]        = hi;
        wf[base + 4096 + f * 512 + lane * 8 + j] = lo;
        return;
    }
    // ---- per-graph node counts via binary search (batch sorted)
    int g = tid;
    int lo = 0, hi = N_NODES;
    while (lo < hi) { int mid = (lo + hi) >> 1; if (batch[mid] < g) lo = mid + 1; else hi = mid; }
    int start = lo;
    lo = 0; hi = N_NODES;
    while (lo < hi) { int mid = (lo + hi) >> 1; if (batch[mid] < g + 1) lo = mid + 1; else hi = mid; }
    cntg[g] = lo - start;
}

// -------- gather (bf16 rows) + prev-layer BN affine computed in-block
// 8 lanes per row; one wave-wide ushort8 load fetches 8 neighbor rows.
__global__ __launch_bounds__(256) void gather_bf16(const unsigned short* __restrict__ hb,
                                                   float* __restrict__ z,
                                                   const int* __restrict__ rp2,
                                                   const int* __restrict__ csr,
                                                   const float* __restrict__ spPrev,
                                                   const float* __restrict__ gammaL,
                                                   const float* __restrict__ betaL) {
    __shared__ float sRed[2 * DIM];
    __shared__ float sSS[2 * DIM];
    int tid = threadIdx.x;

    // issue row-pointer (and self-row) loads BEFORE the stats preamble so
    // they are in flight during the LDS reduction + barriers
    int node = blockIdx.x * 4 + (tid >> 6);     // 12500*4 == 50000: exact
    int lane = tid & 63;
    int c8 = lane & 7, sub = lane >> 3;
    int rbase = (node >> 6) * 65 + (node & 63);
    int e0 = rp2[rbase], end = rp2[rbase + 1];

    if (spPrev) {                       // finalize_stats folded into every block
        if (tid < 2 * DIM) {
            float s = 0.f;
#pragma unroll
            for (int p = 0; p < N_PART; p++) s += spPrev[p * 2 * DIM + tid];
            sRed[tid] = s;
        }
        __syncthreads();
        if (tid < DIM) {
            const float inv_n = 1.0f / (float)N_NODES;
            float mu  = sRed[tid] * inv_n;
            float var = sRed[DIM + tid] * inv_n - mu * mu;
            float sc  = gammaL[tid] / sqrtf(var + BN_EPS);
            sSS[tid]       = sc;
            sSS[DIM + tid] = betaL[tid] - mu * sc;
        }
        __syncthreads();
    }

    int e = e0;
    float degf = 1.f + (float)(end - e);
    float a[8];
#pragma unroll
    for (int i = 0; i < 8; i++) a[i] = 0.f;
    if (sub == 0) {
        short8 sv = *(const short8*)&hb[(size_t)node * DIM + c8 * 8];
#pragma unroll
        for (int i = 0; i < 8; i++) a[i] = bf16_f((unsigned short)sv[i]);
    }
    for (; e + 16 <= end; e += 16) {
        int i0 = csr[e + sub];
        int i1 = csr[e + 8 + sub];
        short8 r0 = *(const short8*)&hb[(size_t)i0 * DIM + c8 * 8];
        short8 r1 = *(const short8*)&hb[(size_t)i1 * DIM + c8 * 8];
#pragma unroll
        for (int i = 0; i < 8; i++)
            a[i] += bf16_f((unsigned short)r0[i]) + bf16_f((unsigned short)r1[i]);
    }
    for (; e + 8 <= end; e += 8) {
        int i0 = csr[e + sub];
        short8 r0 = *(const short8*)&hb[(size_t)i0 * DIM + c8 * 8];
#pragma unroll
        for (int i = 0; i < 8; i++) a[i] += bf16_f((unsigned short)r0[i]);
    }
    int rem = end - e;
    if (sub < rem) {
        short8 r0 = *(const short8*)&hb[(size_t)csr[e + sub] * DIM + c8 * 8];
#pragma unroll
        for (int i = 0; i < 8; i++) a[i] += bf16_f((unsigned short)r0[i]);
    }
#pragma unroll
    for (int i = 0; i < 8; i++) {
        a[i] += __shfl_xor(a[i], 8);
        a[i] += __shfl_xor(a[i], 16);
        a[i] += __shfl_xor(a[i], 32);
    }
    if (sub == 0) {
        int ch = c8 * 8;
        float4 o1, o2;
        if (spPrev) {
            o1.x = fmaf(a[0], sSS[ch + 0], degf * sSS[DIM + ch + 0]);
            o1.y = fmaf(a[1], sSS[ch + 1], degf * sSS[DIM + ch + 1]);
            o1.z = fmaf(a[2], sSS[ch + 2], degf * sSS[DIM + ch + 2]);
            o1.w = fmaf(a[3], sSS[ch + 3], degf * sSS[DIM + ch + 3]);
            o2.x = fmaf(a[4], sSS[ch + 4], degf * sSS[DIM + ch + 4]);
            o2.y = fmaf(a[5], sSS[ch + 5], degf * sSS[DIM + ch + 5]);
            o2.z = fmaf(a[6], sSS[ch + 6], degf * sSS[DIM + ch + 6]);
            o2.w = fmaf(a[7], sSS[ch + 7], degf * sSS[DIM + ch + 7]);
        } else {
            o1.x = a[0]; o1.y = a[1]; o1.z = a[2]; o1.w = a[3];
            o2.x = a[4]; o2.y = a[5]; o2.z = a[6]; o2.w = a[7];
        }
        *(float4*)&z[(size_t)node * DIM + ch] = o1;
        *(float4*)&z[(size_t)node * DIM + ch + 4] = o2;
    }
}

// ------- MFMA MLP: bf16 z' = relu(relu(zW1+B1)W2+B2) + BN partials + raw pool
#define HS_STRIDE 68
__global__ __launch_bounds__(256) void mlp_mfma(const float* __restrict__ z,
    unsigned short* __restrict__ zb,
    const unsigned short* __restrict__ wfL,
    const float* __restrict__ B1, const float* __restrict__ B2,
    float* __restrict__ sums_part, float* __restrict__ praw,
    const int* __restrict__ batch, int write_z) {
    __shared__ float sH[4][16 * HS_STRIDE];
    __shared__ float sSum[2 * DIM];
    __shared__ int   sBatch[64];

    int tid = threadIdx.x, wave = tid >> 6, lane = tid & 63;
    int blk0 = blockIdx.x * 64;
    if (tid < 2 * DIM) sSum[tid] = 0.f;
    if (tid < 64) sBatch[tid] = (blk0 + tid < N_NODES) ? batch[blk0 + tid] : -1;
    __syncthreads();

    int m = lane & 15, quad = lane >> 4;
    int row0 = blk0 + wave * 16;
    int grow = row0 + m;
    int ar = grow < N_NODES ? grow : N_NODES - 1;

    const float4* zr = (const float4*)(z + (size_t)ar * DIM);
    float4 a0 = zr[quad * 2],     a1 = zr[quad * 2 + 1];
    float4 a2 = zr[8 + quad * 2], a3 = zr[8 + quad * 2 + 1];
    short8 Ah0, Al0, Ah1, Al1;
    split8(a0, a1, &Ah0, &Al0);
    split8(a2, a3, &Ah1, &Al1);

    floatx4 acc[4];
#pragma unroll
    for (int nt = 0; nt < 4; nt++) acc[nt] = (floatx4){0.f, 0.f, 0.f, 0.f};
#pragma unroll
    for (int nt = 0; nt < 4; nt++) {
#pragma unroll
        for (int ks = 0; ks < 2; ks++) {
            const short8 Bh = *(const short8*)(wfL + (nt * 2 + ks) * 512 + lane * 8);
            const short8 Bl = *(const short8*)(wfL + 4096 + (nt * 2 + ks) * 512 + lane * 8);
            short8 Ahf = ks ? Ah1 : Ah0;
            short8 Alf = ks ? Al1 : Al0;
            acc[nt] = __builtin_amdgcn_mfma_f32_16x16x32_bf16(Ahf, Bh, acc[nt], 0, 0, 0);
            acc[nt] = __builtin_amdgcn_mfma_f32_16x16x32_bf16(Ahf, Bl, acc[nt], 0, 0, 0);
            acc[nt] = __builtin_amdgcn_mfma_f32_16x16x32_bf16(Alf, Bh, acc[nt], 0, 0, 0);
        }
    }

    float* Hs = sH[wave];
#pragma unroll
    for (int nt = 0; nt < 4; nt++) {
        int col = nt * 16 + m;
        float b = B1[col];
#pragma unroll
        for (int r = 0; r < 4; r++) {
            int lr = quad * 4 + r;
            Hs[lr * HS_STRIDE + col] = fmaxf(acc[nt][r] + b, 0.f);
        }
    }
    float4 h0 = *(const float4*)&Hs[m * HS_STRIDE + quad * 8];
    float4 h1 = *(const float4*)&Hs[m * HS_STRIDE + quad * 8 + 4];
    float4 h2 = *(const float4*)&Hs[m * HS_STRIDE + 32 + quad * 8];
    float4 h3 = *(const float4*)&Hs[m * HS_STRIDE + 32 + quad * 8 + 4];
    short8 Hh0, Hl0, Hh1, Hl1;
    split8(h0, h1, &Hh0, &Hl0);
    split8(h2, h3, &Hh1, &Hl1);

    floatx4 acc2[4];
#pragma unroll
    for (int nt = 0; nt < 4; nt++) acc2[nt] = (floatx4){0.f, 0.f, 0.f, 0.f};
    const unsigned short* wg2 = wfL + 8192;
#pragma unroll
    for (int nt = 0; nt < 4; nt++) {
#pragma unroll
        for (int ks = 0; ks < 2; ks++) {
            const short8 Bh = *(const short8*)(wg2 + (nt * 2 + ks) * 512 + lane * 8);
            const short8 Bl = *(const short8*)(wg2 + 4096 + (nt * 2 + ks) * 512 + lane * 8);
            short8 Ahf = ks ? Hh1 : Hh0;
            short8 Alf = ks ? Hl1 : Hl0;
            acc2[nt] = __builtin_amdgcn_mfma_f32_16x16x32_bf16(Ahf, Bh, acc2[nt], 0, 0, 0);
            acc2[nt] = __builtin_amdgcn_mfma_f32_16x16x32_bf16(Ahf, Bl, acc2[nt], 0, 0, 0);
            acc2[nt] = __builtin_amdgcn_mfma_f32_16x16x32_bf16(Alf, Bh, acc2[nt], 0, 0, 0);
        }
    }

    // ---- epilogue: bf16 z write + BN partials + per-graph raw pooling
    int widx = wave * 16;
    int gfirst = sBatch[widx], glast = sBatch[widx + 15];
    bool uni = (gfirst == glast) && (gfirst >= 0);
#pragma unroll
    for (int nt = 0; nt < 4; nt++) {
        int col = nt * 16 + m;
        float b = B2[col];
        float vv[4];
        float s = 0.f, s2 = 0.f;
#pragma unroll
        for (int r = 0; r < 4; r++) {
            int gr = row0 + quad * 4 + r;
            float v = fmaxf(acc2[nt][r] + b, 0.f);
            if (gr < N_NODES) {
                if (write_z) zb[(size_t)gr * DIM + col] = bf16_rn(v);
                s += v;
                s2 = fmaf(v, v, s2);
                vv[r] = v;
            } else {
                vv[r] = 0.f;
            }
        }
        float sf = s, s2f = s2;
        sf  += __shfl_xor(sf, 16);  sf  += __shfl_xor(sf, 32);
        s2f += __shfl_xor(s2f, 16); s2f += __shfl_xor(s2f, 32);
        if (quad == 0) {
            atomicAdd(&sSum[col], sf);
            atomicAdd(&sSum[DIM + col], s2f);
            if (uni) atomicAdd(&praw[(size_t)gfirst * DIM + col], sf);
        }
        if (!uni) {
            int cur = -1; float run = 0.f;
#pragma unroll
            for (int r = 0; r < 4; r++) {
                int g = sBatch[widx + quad * 4 + r];
                if (g != cur) {
                    if (cur >= 0 && run != 0.f)
                        atomicAdd(&praw[(size_t)cur * DIM + col], run);
                    run = 0.f; cur = g;
                }
                run += vv[r];
            }
            if (cur >= 0 && run != 0.f)
                atomicAdd(&praw[(size_t)cur * DIM + col], run);
        }
    }
    __syncthreads();
    if (tid < 2 * DIM)
        atomicAdd(&sums_part[(size_t)(blockIdx.x & (N_PART - 1)) * 2 * DIM + tid], sSum[tid]);
}

// ---------- final 2-layer MLP; pooled row assembled inline from partials
__global__ __launch_bounds__(192) void final_mlp(const float* __restrict__ sums_part,
    const float* __restrict__ praw,
    const float* __restrict__ gamma, const float* __restrict__ beta,
    const int* __restrict__ cntg,
    const float* __restrict__ PW1, const float* __restrict__ PB1,
    const float* __restrict__ PW2, const float* __restrict__ PB2,
    float* __restrict__ out) {
    __shared__ float row[D3];
    __shared__ float hid[D3];
    int g = blockIdx.x, j = threadIdx.x;
    {   // inline assemble_pooled for element (g, j)
        int L = j >> 6, c = j & 63;
        const float* sp = sums_part + (size_t)L * N_PART * 2 * DIM;
        float s = 0.f, q = 0.f;
#pragma unroll
        for (int p = 0; p < N_PART; p++) {
            s += sp[p * 2 * DIM + c];
            q += sp[p * 2 * DIM + DIM + c];
        }
        const float inv_n = 1.0f / (float)N_NODES;
        float mu  = s * inv_n;
        float var = q * inv_n - mu * mu;
        float sc  = gamma[L * DIM + c] / sqrtf(var + BN_EPS);
        float sh  = beta[L * DIM + c] - mu * sc;
        row[j] = fmaf(sc, praw[((size_t)L * N_GRAPHS + g) * DIM + c],
                      (float)cntg[g] * sh);
    }
    __syncthreads();
    float acc = PB1[j];
    for (int k = 0; k < D3; k++) acc = fmaf(row[k], PW1[k * D3 + j], acc);
    hid[j] = fmaxf(acc, 0.f);
    __syncthreads();
    float acc2 = PB2[j];
    for (int k = 0; k < D3; k++) acc2 = fmaf(hid[k], PW2[k * D3 + j], acc2);
    out[(size_t)g * D3 + j] = acc2;
}

extern "C" void kernel_launch(void* const* d_in, const int* in_sizes, int n_in,
                              void* d_out, int out_size, void* d_ws, size_t ws_size,
                              hipStream_t stream) {
    const float* x     = (const float*)d_in[0];
    const int*   ei    = (const int*)d_in[1];
    const int*   batch = (const int*)d_in[2];
    const float* W1    = (const float*)d_in[3];
    const float* B1    = (const float*)d_in[4];
    const float* W2    = (const float*)d_in[5];
    const float* B2    = (const float*)d_in[6];
    const float* gamma = (const float*)d_in[7];
    const float* beta  = (const float*)d_in[8];
    const float* PW1   = (const float*)d_in[9];
    const float* PB1   = (const float*)d_in[10];
    const float* PW2   = (const float*)d_in[11];
    const float* PB2   = (const float*)d_in[12];
    float* out = (float*)d_out;

    // -------- workspace layout (~50 MB of 256 MB)
    float*    bufA  = (float*)d_ws;                              // 3,200,000 f (gather out)
    unsigned short* zb = (unsigned short*)(bufA + (size_t)N_NODES * DIM); // 3,200,000 u16
    unsigned short* xb = zb + (size_t)N_NODES * DIM;             // 3,200,000 u16
    unsigned* ebuf  = (unsigned*)(xb + (size_t)N_NODES * DIM);   // 782*2048 u32
    int*      csr   = (int*)(ebuf + (size_t)NBKT * ECAP);        // 782*2048 i (fixed regions)
    int*      rp2   = csr + NBKT * ECAP;                         // 782*65 -> 50,832
    int*      bcnt  = rp2 + 50832;                               // 784 i (written fully)
    int*      counts = bcnt + 784;                               // 153,272 i (written fully)
    int*      offs   = counts + NBKT * NPB;                      // 153,272 i (written fully)
    unsigned short* wfrag = (unsigned short*)(offs + NBKT * NPB); // 49,152 u16
    int*      cntg  = (int*)(wfrag + 49152);                     // 256 i (written fully)
    // ---- accumulator region (zeroed by pass1_hist)
    float*    sums_part = (float*)(cntg + N_GRAPHS);             // 3*8*128 = 3,072 f
    float*    praw  = sums_part + N_LAYERS * N_PART * 2 * DIM;   // 49,152 f

    const int* src = ei;
    const int* dst = ei + N_EDGES;

    // -------- CSR build: deterministic two-pass partition (no global atomics)
    pass1_hist<<<NPB, 256, 0, stream>>>(dst, counts, (float4*)sums_part);
    bucket_scan<<<NBKT, 256, 0, stream>>>(counts, offs, bcnt);
    pass2_scatter<<<NPB, 256, 0, stream>>>(src, dst, offs, ebuf);
    sort_and_setup<<<NBKT + CVT_BLOCKS + PREP_BLOCKS + 1, 256, 0, stream>>>(
        ebuf, bcnt, csr, rp2, x, xb, W1, W2, wfrag, batch, cntg);

    // -------- layers: gather(+in-block BN stats) -> mlp(bf16 z + stats + pool)
    const int GB = (N_NODES + 3) / 4;     // 12500
    const int MB = (N_NODES + 63) / 64;   // 782
    for (int L = 0; L < N_LAYERS; ++L) {
        int write_z = (L < N_LAYERS - 1);
        gather_bf16<<<GB, 256, 0, stream>>>(
            (L == 0) ? xb : zb, bufA, rp2, csr,
            (L == 0) ? (const float*)nullptr : sums_part + (size_t)(L - 1) * N_PART * 2 * DIM,
            gamma + (size_t)(L ? L - 1 : 0) * DIM,
            beta + (size_t)(L ? L - 1 : 0) * DIM);
        mlp_mfma<<<MB, 256, 0, stream>>>(
            bufA, zb,
            wfrag + (size_t)L * 2 * 8192, B1 + (size_t)L * DIM, B2 + (size_t)L * DIM,
            sums_part + (size_t)L * N_PART * 2 * DIM,
            praw + (size_t)L * N_GRAPHS * DIM, batch, write_z);
    }

    final_mlp<<<N_GRAPHS, 192, 0, stream>>>(
        sums_part, praw, gamma, beta, cntg, PW1, PB1, PW2, PB2, out);
}

// Round 2
// 217.906 us; speedup vs baseline: 1.1702x; 1.1702x over previous
//
#include <hip/hip_runtime.h>

#define N_NODES 50000
#define N_EDGES 800000
#define DIM 64
#define N_LAYERS 3
#define N_GRAPHS 256
#define BN_EPS 1e-5f
#define D3 (DIM * N_LAYERS)
#define N_PART 8
#define NBKT 782          // ceil(50000/64) destination buckets
#define NPB 196           // partition blocks (4096 edges each)
#define ECAP 2048         // fixed capacity per bucket (mean 1023, sigma ~32)
#define CVT_BLOCKS 3125   // convert_x blocks (800,000 float4 / 256)
#define PREP_BLOCKS 96    // prep_weights blocks (24,576 / 256)
#define ZF4 13056         // float4s to zero: (3*8*128 + 3*256*64)/4

typedef __attribute__((ext_vector_type(8))) short short8;
typedef __attribute__((ext_vector_type(4))) float floatx4;

// ---------------------------------------------------------- bf16 split utils
__device__ inline unsigned short bf16_rn(float f) {
    unsigned u = __float_as_uint(f);
    u += 0x7FFF + ((u >> 16) & 1);
    return (unsigned short)(u >> 16);
}
__device__ inline float bf16_f(unsigned short b) {
    return __uint_as_float(((unsigned)b) << 16);
}
__device__ inline void split8(float4 a, float4 b, short8* hi, short8* lo) {
    float v[8] = {a.x, a.y, a.z, a.w, b.x, b.y, b.z, b.w};
#pragma unroll
    for (int i = 0; i < 8; i++) {
        unsigned short h = bf16_rn(v[i]);
        (*hi)[i] = (short)h;
        (*lo)[i] = (short)bf16_rn(v[i] - bf16_f(h));
    }
}

// -------- pass 1: per-block LDS hist -> counts[bucket][block]; also zeros
// the sums_part/praw accumulator region (replaces a hipMemsetAsync dispatch)
__global__ __launch_bounds__(256) void pass1_hist(const int* __restrict__ dst,
                                                  int* __restrict__ counts,
                                                  float4* __restrict__ zbuf) {
    int zi = blockIdx.x * 256 + threadIdx.x;
    if (zi < ZF4) zbuf[zi] = (float4){0.f, 0.f, 0.f, 0.f};
    __shared__ int hcnt[NBKT];
    for (int i = threadIdx.x; i < NBKT; i += 256) hcnt[i] = 0;
    __syncthreads();
    int base = blockIdx.x * 4096;
#pragma unroll
    for (int k = 0; k < 16; k++) {
        int e = base + k * 256 + threadIdx.x;
        if (e < N_EDGES) atomicAdd(&hcnt[dst[e] >> 6], 1);   // LDS atomic (native)
    }
    __syncthreads();
    for (int i = threadIdx.x; i < NBKT; i += 256)
        counts[i * NPB + blockIdx.x] = hcnt[i];
}

// -------- per-bucket exclusive scan over the 196 block counts -> offs, totals
__global__ __launch_bounds__(256) void bucket_scan(const int* __restrict__ counts,
                                                   int* __restrict__ offs,
                                                   int* __restrict__ bcnt) {
    __shared__ int s[256];
    int b = blockIdx.x, t = threadIdx.x;
    int v = (t < NPB) ? counts[b * NPB + t] : 0;
    s[t] = v;
    __syncthreads();
    for (int off = 1; off < 256; off <<= 1) {
        int u = (t >= off) ? s[t - off] : 0;
        __syncthreads();
        s[t] += u;
        __syncthreads();
    }
    if (t < NPB) offs[b * NPB + t] = s[t] - v;
    if (t == NPB - 1) bcnt[b] = s[t];
}

// -------- pass 2: deterministic scatter via LDS position counters
__global__ __launch_bounds__(256) void pass2_scatter(const int* __restrict__ src,
                                                     const int* __restrict__ dst,
                                                     const int* __restrict__ offs,
                                                     unsigned* __restrict__ ebuf) {
    __shared__ int loff[NBKT];
    int blk = blockIdx.x;
    for (int i = threadIdx.x; i < NBKT; i += 256)
        loff[i] = offs[i * NPB + blk];
    __syncthreads();
    int base = blk * 4096;
#pragma unroll
    for (int k = 0; k < 16; k++) {
        int e = base + k * 256 + threadIdx.x;
        if (e < N_EDGES) {
            int d = dst[e];
            int b = d >> 6;
            int pos = atomicAdd(&loff[b], 1);     // LDS int atomic (native)
            ebuf[(size_t)b * ECAP + pos] = ((unsigned)src[e] << 6) | (unsigned)(d & 63);
        }
    }
}

// ===== fused: bucket counting-sort (blocks [0,NBKT)) + setup work
__global__ __launch_bounds__(256) void sort_and_setup(
    const unsigned* __restrict__ ebuf, const int* __restrict__ bcnt,
    int* __restrict__ csr, int* __restrict__ rp2,
    const float* __restrict__ x, unsigned short* __restrict__ xb,
    const float* __restrict__ W1, const float* __restrict__ W2,
    unsigned short* __restrict__ wf,
    const int* __restrict__ batch, int* __restrict__ cntg) {
    int blk = blockIdx.x, tid = threadIdx.x;

    if (blk < NBKT) {                     // ---- bucket counting sort
        __shared__ unsigned ent[ECAP];
        __shared__ int cnt[64], basea[64], fill[64];
        int b = blk;
        int start = b * ECAP;
        int T = bcnt[b];
        const unsigned* eb = ebuf + (size_t)b * ECAP;
        if (tid < 64) cnt[tid] = 0;
        for (int i = tid; i < T; i += 256) ent[i] = eb[i];
        __syncthreads();
        for (int i = tid; i < T; i += 256) atomicAdd(&cnt[ent[i] & 63], 1);
        __syncthreads();
        if (tid < 64) {
            int v = cnt[tid], xp = v;
#pragma unroll
            for (int off = 1; off < 64; off <<= 1) {
                int y = __shfl_up(xp, off);
                if (tid >= off) xp += y;
            }
            basea[tid] = xp - v;
            fill[tid] = 0;
            rp2[b * 65 + tid] = start + xp - v;
            if (tid == 63) rp2[b * 65 + 64] = start + xp;
        }
        __syncthreads();
        for (int i = tid; i < T; i += 256) {
            unsigned e = ent[i];
            int c = e & 63;
            int pos = basea[c] + atomicAdd(&fill[c], 1);
            csr[start + pos] = (int)(e >> 6);
        }
        return;
    }
    int sb = blk - NBKT;
    if (sb < CVT_BLOCKS) {                // ---- convert x to bf16
        int i = sb * 256 + tid;
        float4 v = ((const float4*)x)[i];
        ushort4 o;
        o.x = bf16_rn(v.x); o.y = bf16_rn(v.y);
        o.z = bf16_rn(v.z); o.w = bf16_rn(v.w);
        ((ushort4*)xb)[i] = o;
        return;
    }
    sb -= CVT_BLOCKS;
    if (sb < PREP_BLOCKS) {               // ---- pack weight fragments
        int idx = sb * 256 + tid;
        int j    = idx & 7;
        int lane = (idx >> 3) & 63;
        int ks   = (idx >> 9) & 1;
        int nt   = (idx >> 10) & 3;
        int gemm = (idx >> 12) & 1;
        int layer = idx >> 13;
        int n = nt * 16 + (lane & 15);
        int k = ks * 32 + (lane >> 4) * 8 + j;
        const float* W = (gemm ? W2 : W1) + (size_t)layer * DIM * DIM;
        float w = W[k * DIM + n];
        unsigned short hi = bf16_rn(w);
        unsigned short lo = bf16_rn(w - bf16_f(hi));
        size_t base = ((size_t)layer * 2 + gemm) * 8192;
        int f = nt * 2 + ks;
        wf[base + f * 512 + lane * 8 + j]        = hi;
        wf[base + 4096 + f * 512 + lane * 8 + j] = lo;
        return;
    }
    // ---- per-graph node counts via binary search (batch sorted)
    int g = tid;
    int lo = 0, hi = N_NODES;
    while (lo < hi) { int mid = (lo + hi) >> 1; if (batch[mid] < g) lo = mid + 1; else hi = mid; }
    int start = lo;
    lo = 0; hi = N_NODES;
    while (lo < hi) { int mid = (lo + hi) >> 1; if (batch[mid] < g + 1) lo = mid + 1; else hi = mid; }
    cntg[g] = lo - start;
}

// ===================== fused per-layer kernel =====================
// Block = 64 nodes = one CSR bucket.
//   Phase A: BN scale/shift of previous layer from partials (L>0)
//   Phase B: gather — 32 groups of 8 lanes; group g owns rows g and g+32;
//            lane c8 owns channel chunk [c8*8, c8*8+8). No cross-lane reduce.
//            Result (with prev-BN affine applied) -> LDS z-tile.
//   Phase C: MFMA MLP (identical math to old mlp_mfma, A-fragments from LDS)
#define HS_STRIDE 68
#define SZ_STR 68
__global__ __launch_bounds__(256) void layer_fused(
    const unsigned short* __restrict__ hb,   // input node rows (bf16)
    unsigned short* __restrict__ zb,         // output node rows (bf16), if write_z
    const int* __restrict__ rp2, const int* __restrict__ csr,
    const float* __restrict__ spPrev,        // null for layer 0
    const float* __restrict__ gammaP, const float* __restrict__ betaP,
    const unsigned short* __restrict__ wfL,
    const float* __restrict__ B1, const float* __restrict__ B2,
    float* __restrict__ sums_part, float* __restrict__ praw,
    const int* __restrict__ batch, int write_z) {
    __shared__ float sZ[64 * SZ_STR];
    __shared__ float sH[4][16 * HS_STRIDE];
    __shared__ float sSS[2 * DIM];
    __shared__ float sSum[2 * DIM];
    __shared__ int   sRP[65];
    __shared__ int   sBatch[64];

    int tid = threadIdx.x;
    int blk = blockIdx.x;
    int blk0 = blk * 64;

    if (tid < 65) sRP[tid] = rp2[blk * 65 + tid];
    if (tid < 2 * DIM) sSum[tid] = 0.f;
    if (tid < 64) sBatch[tid] = (blk0 + tid < N_NODES) ? batch[blk0 + tid] : -1;

    if (spPrev) {                       // finalize prev-layer BN stats
        float* sRed = sH[0];            // scratch (sH unused until phase C)
        if (tid < 2 * DIM) {
            float s = 0.f;
#pragma unroll
            for (int p = 0; p < N_PART; p++) s += spPrev[p * 2 * DIM + tid];
            sRed[tid] = s;
        }
        __syncthreads();
        if (tid < DIM) {
            const float inv_n = 1.0f / (float)N_NODES;
            float mu  = sRed[tid] * inv_n;
            float var = sRed[DIM + tid] * inv_n - mu * mu;
            float sc  = gammaP[tid] / sqrtf(var + BN_EPS);
            sSS[tid]       = sc;
            sSS[DIM + tid] = betaP[tid] - mu * sc;
        }
    }
    __syncthreads();

    // ---------------- Phase B: gather into sZ ----------------
    {
        int c8 = tid & 7, grp = tid >> 3;      // 32 groups of 8 lanes
        const bool aff = (spPrev != nullptr);
#pragma unroll
        for (int p = 0; p < 2; ++p) {
            int t = grp + 32 * p;
            int nodeg = blk0 + t;
            float a[8];
            if (nodeg < N_NODES) {
                int e0 = sRP[t], end = sRP[t + 1];
                short8 sv = *(const short8*)&hb[(size_t)nodeg * DIM + c8 * 8];
#pragma unroll
                for (int i = 0; i < 8; i++) a[i] = bf16_f((unsigned short)sv[i]);
                int e = e0;
                for (; e + 4 <= end; e += 4) {
                    int i0 = csr[e], i1 = csr[e + 1], i2 = csr[e + 2], i3 = csr[e + 3];
                    short8 r0 = *(const short8*)&hb[(size_t)i0 * DIM + c8 * 8];
                    short8 r1 = *(const short8*)&hb[(size_t)i1 * DIM + c8 * 8];
                    short8 r2 = *(const short8*)&hb[(size_t)i2 * DIM + c8 * 8];
                    short8 r3 = *(const short8*)&hb[(size_t)i3 * DIM + c8 * 8];
#pragma unroll
                    for (int i = 0; i < 8; i++)
                        a[i] += (bf16_f((unsigned short)r0[i]) + bf16_f((unsigned short)r1[i]))
                              + (bf16_f((unsigned short)r2[i]) + bf16_f((unsigned short)r3[i]));
                }
                for (; e < end; ++e) {
                    int i0 = csr[e];
                    short8 r0 = *(const short8*)&hb[(size_t)i0 * DIM + c8 * 8];
#pragma unroll
                    for (int i = 0; i < 8; i++) a[i] += bf16_f((unsigned short)r0[i]);
                }
                if (aff) {
                    float degf = 1.f + (float)(end - e0);
#pragma unroll
                    for (int i = 0; i < 8; i++)
                        a[i] = fmaf(a[i], sSS[c8 * 8 + i], degf * sSS[DIM + c8 * 8 + i]);
                }
            } else {
#pragma unroll
                for (int i = 0; i < 8; i++) a[i] = 0.f;
            }
            float4 o1, o2;
            o1.x = a[0]; o1.y = a[1]; o1.z = a[2]; o1.w = a[3];
            o2.x = a[4]; o2.y = a[5]; o2.z = a[6]; o2.w = a[7];
            *(float4*)&sZ[t * SZ_STR + c8 * 8]     = o1;
            *(float4*)&sZ[t * SZ_STR + c8 * 8 + 4] = o2;
        }
    }
    __syncthreads();

    // ---------------- Phase C: MFMA MLP ----------------
    int wave = tid >> 6, lane = tid & 63;
    int m = lane & 15, quad = lane >> 4;
    int row0 = blk0 + wave * 16;
    int lrow = wave * 16 + m;

    float4 a0 = *(const float4*)&sZ[lrow * SZ_STR + quad * 8];
    float4 a1 = *(const float4*)&sZ[lrow * SZ_STR + quad * 8 + 4];
    float4 a2 = *(const float4*)&sZ[lrow * SZ_STR + 32 + quad * 8];
    float4 a3 = *(const float4*)&sZ[lrow * SZ_STR + 32 + quad * 8 + 4];
    short8 Ah0, Al0, Ah1, Al1;
    split8(a0, a1, &Ah0, &Al0);
    split8(a2, a3, &Ah1, &Al1);

    floatx4 acc[4];
#pragma unroll
    for (int nt = 0; nt < 4; nt++) acc[nt] = (floatx4){0.f, 0.f, 0.f, 0.f};
#pragma unroll
    for (int nt = 0; nt < 4; nt++) {
#pragma unroll
        for (int ks = 0; ks < 2; ks++) {
            const short8 Bh = *(const short8*)(wfL + (nt * 2 + ks) * 512 + lane * 8);
            const short8 Bl = *(const short8*)(wfL + 4096 + (nt * 2 + ks) * 512 + lane * 8);
            short8 Ahf = ks ? Ah1 : Ah0;
            short8 Alf = ks ? Al1 : Al0;
            acc[nt] = __builtin_amdgcn_mfma_f32_16x16x32_bf16(Ahf, Bh, acc[nt], 0, 0, 0);
            acc[nt] = __builtin_amdgcn_mfma_f32_16x16x32_bf16(Ahf, Bl, acc[nt], 0, 0, 0);
            acc[nt] = __builtin_amdgcn_mfma_f32_16x16x32_bf16(Alf, Bh, acc[nt], 0, 0, 0);
        }
    }

    float* Hs = sH[wave];
#pragma unroll
    for (int nt = 0; nt < 4; nt++) {
        int col = nt * 16 + m;
        float b = B1[col];
#pragma unroll
        for (int r = 0; r < 4; r++) {
            int lr = quad * 4 + r;
            Hs[lr * HS_STRIDE + col] = fmaxf(acc[nt][r] + b, 0.f);
        }
    }
    float4 h0 = *(const float4*)&Hs[m * HS_STRIDE + quad * 8];
    float4 h1 = *(const float4*)&Hs[m * HS_STRIDE + quad * 8 + 4];
    float4 h2 = *(const float4*)&Hs[m * HS_STRIDE + 32 + quad * 8];
    float4 h3 = *(const float4*)&Hs[m * HS_STRIDE + 32 + quad * 8 + 4];
    short8 Hh0, Hl0, Hh1, Hl1;
    split8(h0, h1, &Hh0, &Hl0);
    split8(h2, h3, &Hh1, &Hl1);

    floatx4 acc2[4];
#pragma unroll
    for (int nt = 0; nt < 4; nt++) acc2[nt] = (floatx4){0.f, 0.f, 0.f, 0.f};
    const unsigned short* wg2 = wfL + 8192;
#pragma unroll
    for (int nt = 0; nt < 4; nt++) {
#pragma unroll
        for (int ks = 0; ks < 2; ks++) {
            const short8 Bh = *(const short8*)(wg2 + (nt * 2 + ks) * 512 + lane * 8);
            const short8 Bl = *(const short8*)(wg2 + 4096 + (nt * 2 + ks) * 512 + lane * 8);
            short8 Ahf = ks ? Hh1 : Hh0;
            short8 Alf = ks ? Hl1 : Hl0;
            acc2[nt] = __builtin_amdgcn_mfma_f32_16x16x32_bf16(Ahf, Bh, acc2[nt], 0, 0, 0);
            acc2[nt] = __builtin_amdgcn_mfma_f32_16x16x32_bf16(Ahf, Bl, acc2[nt], 0, 0, 0);
            acc2[nt] = __builtin_amdgcn_mfma_f32_16x16x32_bf16(Alf, Bh, acc2[nt], 0, 0, 0);
        }
    }

    // ---- epilogue: bf16 z write + BN partials + per-graph raw pooling
    int widx = wave * 16;
    int gfirst = sBatch[widx], glast = sBatch[widx + 15];
    bool uni = (gfirst == glast) && (gfirst >= 0);
#pragma unroll
    for (int nt = 0; nt < 4; nt++) {
        int col = nt * 16 + m;
        float b = B2[col];
        float vv[4];
        float s = 0.f, s2 = 0.f;
#pragma unroll
        for (int r = 0; r < 4; r++) {
            int gr = row0 + quad * 4 + r;
            float v = fmaxf(acc2[nt][r] + b, 0.f);
            if (gr < N_NODES) {
                if (write_z) zb[(size_t)gr * DIM + col] = bf16_rn(v);
                s += v;
                s2 = fmaf(v, v, s2);
                vv[r] = v;
            } else {
                vv[r] = 0.f;
            }
        }
        float sf = s, s2f = s2;
        sf  += __shfl_xor(sf, 16);  sf  += __shfl_xor(sf, 32);
        s2f += __shfl_xor(s2f, 16); s2f += __shfl_xor(s2f, 32);
        if (quad == 0) {
            atomicAdd(&sSum[col], sf);
            atomicAdd(&sSum[DIM + col], s2f);
            if (uni) atomicAdd(&praw[(size_t)gfirst * DIM + col], sf);
        }
        if (!uni) {
            int cur = -1; float run = 0.f;
#pragma unroll
            for (int r = 0; r < 4; r++) {
                int g = sBatch[widx + quad * 4 + r];
                if (g != cur) {
                    if (cur >= 0 && run != 0.f)
                        atomicAdd(&praw[(size_t)cur * DIM + col], run);
                    run = 0.f; cur = g;
                }
                run += vv[r];
            }
            if (cur >= 0 && run != 0.f)
                atomicAdd(&praw[(size_t)cur * DIM + col], run);
        }
    }
    __syncthreads();
    if (tid < 2 * DIM)
        atomicAdd(&sums_part[(size_t)(blockIdx.x & (N_PART - 1)) * 2 * DIM + tid], sSum[tid]);
}

// ---------- final 2-layer MLP; pooled row assembled inline from partials
__global__ __launch_bounds__(192) void final_mlp(const float* __restrict__ sums_part,
    const float* __restrict__ praw,
    const float* __restrict__ gamma, const float* __restrict__ beta,
    const int* __restrict__ cntg,
    const float* __restrict__ PW1, const float* __restrict__ PB1,
    const float* __restrict__ PW2, const float* __restrict__ PB2,
    float* __restrict__ out) {
    __shared__ float row[D3];
    __shared__ float hid[D3];
    int g = blockIdx.x, j = threadIdx.x;
    {   // inline assemble_pooled for element (g, j)
        int L = j >> 6, c = j & 63;
        const float* sp = sums_part + (size_t)L * N_PART * 2 * DIM;
        float s = 0.f, q = 0.f;
#pragma unroll
        for (int p = 0; p < N_PART; p++) {
            s += sp[p * 2 * DIM + c];
            q += sp[p * 2 * DIM + DIM + c];
        }
        const float inv_n = 1.0f / (float)N_NODES;
        float mu  = s * inv_n;
        float var = q * inv_n - mu * mu;
        float sc  = gamma[L * DIM + c] / sqrtf(var + BN_EPS);
        float sh  = beta[L * DIM + c] - mu * sc;
        row[j] = fmaf(sc, praw[((size_t)L * N_GRAPHS + g) * DIM + c],
                      (float)cntg[g] * sh);
    }
    __syncthreads();
    float acc = PB1[j];
    for (int k = 0; k < D3; k++) acc = fmaf(row[k], PW1[k * D3 + j], acc);
    hid[j] = fmaxf(acc, 0.f);
    __syncthreads();
    float acc2 = PB2[j];
    for (int k = 0; k < D3; k++) acc2 = fmaf(hid[k], PW2[k * D3 + j], acc2);
    out[(size_t)g * D3 + j] = acc2;
}

extern "C" void kernel_launch(void* const* d_in, const int* in_sizes, int n_in,
                              void* d_out, int out_size, void* d_ws, size_t ws_size,
                              hipStream_t stream) {
    const float* x     = (const float*)d_in[0];
    const int*   ei    = (const int*)d_in[1];
    const int*   batch = (const int*)d_in[2];
    const float* W1    = (const float*)d_in[3];
    const float* B1    = (const float*)d_in[4];
    const float* W2    = (const float*)d_in[5];
    const float* B2    = (const float*)d_in[6];
    const float* gamma = (const float*)d_in[7];
    const float* beta  = (const float*)d_in[8];
    const float* PW1   = (const float*)d_in[9];
    const float* PB1   = (const float*)d_in[10];
    const float* PW2   = (const float*)d_in[11];
    const float* PB2   = (const float*)d_in[12];
    float* out = (float*)d_out;

    // -------- workspace layout (~50 MB of 256 MB)
    float*    bufA  = (float*)d_ws;                              // 3,200,000 f (now: zbB)
    unsigned short* zb = (unsigned short*)(bufA + (size_t)N_NODES * DIM); // 3,200,000 u16
    unsigned short* xb = zb + (size_t)N_NODES * DIM;             // 3,200,000 u16
    unsigned* ebuf  = (unsigned*)(xb + (size_t)N_NODES * DIM);   // 782*2048 u32
    int*      csr   = (int*)(ebuf + (size_t)NBKT * ECAP);        // 782*2048 i (fixed regions)
    int*      rp2   = csr + NBKT * ECAP;                         // 782*65 -> 50,832
    int*      bcnt  = rp2 + 50832;                               // 784 i (written fully)
    int*      counts = bcnt + 784;                               // 153,272 i (written fully)
    int*      offs   = counts + NBKT * NPB;                      // 153,272 i (written fully)
    unsigned short* wfrag = (unsigned short*)(offs + NBKT * NPB); // 49,152 u16
    int*      cntg  = (int*)(wfrag + 49152);                     // 256 i (written fully)
    // ---- accumulator region (zeroed by pass1_hist)
    float*    sums_part = (float*)(cntg + N_GRAPHS);             // 3*8*128 = 3,072 f
    float*    praw  = sums_part + N_LAYERS * N_PART * 2 * DIM;   // 49,152 f

    unsigned short* zbB = (unsigned short*)bufA;   // double-buffer for z (6.4 MB of 12.8)

    const int* src = ei;
    const int* dst = ei + N_EDGES;

    // -------- CSR build: deterministic two-pass partition (no global atomics)
    pass1_hist<<<NPB, 256, 0, stream>>>(dst, counts, (float4*)sums_part);
    bucket_scan<<<NBKT, 256, 0, stream>>>(counts, offs, bcnt);
    pass2_scatter<<<NPB, 256, 0, stream>>>(src, dst, offs, ebuf);
    sort_and_setup<<<NBKT + CVT_BLOCKS + PREP_BLOCKS + 1, 256, 0, stream>>>(
        ebuf, bcnt, csr, rp2, x, xb, W1, W2, wfrag, batch, cntg);

    // -------- fused layers: gather(+prev BN)->MLP->(bf16 z + stats + pool)
    const int MB = (N_NODES + 63) / 64;   // 782
    const unsigned short* inb[3]  = {xb, zb, zbB};
    unsigned short*       outb[3] = {zb, zbB, zb};   // L2 output unused
    for (int L = 0; L < N_LAYERS; ++L) {
        int write_z = (L < N_LAYERS - 1);
        layer_fused<<<MB, 256, 0, stream>>>(
            inb[L], outb[L], rp2, csr,
            (L == 0) ? (const float*)nullptr : sums_part + (size_t)(L - 1) * N_PART * 2 * DIM,
            gamma + (size_t)(L ? L - 1 : 0) * DIM,
            beta + (size_t)(L ? L - 1 : 0) * DIM,
            wfrag + (size_t)L * 2 * 8192, B1 + (size_t)L * DIM, B2 + (size_t)L * DIM,
            sums_part + (size_t)L * N_PART * 2 * DIM,
            praw + (size_t)L * N_GRAPHS * DIM, batch, write_z);
    }

    final_mlp<<<N_GRAPHS, 192, 0, stream>>>(
        sums_part, praw, gamma, beta, cntg, PW1, PB1, PW2, PB2, out);
}